// Round 3
// baseline (574.088 us; speedup 1.0000x reference)
//
#include <hip/hip_runtime.h>
#include <math.h>

// Problem constants (from reference)
#define KN    20000   // vocab
#define KH    40      // LSTM hidden
#define KDW   128     // W_down width
#define KND   16      // noise dim
#define KRW   8       // rw_len
#define KNS   512     // n_sample
#define KNCH  313     // ceil(KN / 64) wave-chunks of 64 cols
#define KEPS  1e-20f
#define KLN2  0.69314718055994531f

__device__ __forceinline__ float sigmoidf_(float x) { return 1.0f / (1.0f + expf(-x)); }

// pack (score, col) into a monotone-increasing u64 key; larger = better.
// ties on score -> smaller col wins (low field = ~col).
__device__ __forceinline__ unsigned long long packsc_(float v, int col) {
  unsigned u = __float_as_uint(v);
  unsigned key = (u >> 31) ? ~u : (u | 0x80000000u);
  return ((unsigned long long)key << 32) | (unsigned)(~col);
}

// ---------------- init: 3-layer MLP (h0,c0) + LSTM step 0 (x=0) ----------------
__global__ void k_init(const float* __restrict__ z,
                       const float* __restrict__ l1w, const float* __restrict__ l1b,
                       const float* __restrict__ l2w, const float* __restrict__ l2b,
                       const float* __restrict__ l3w, const float* __restrict__ l3b,
                       const float* __restrict__ b_ih, const float* __restrict__ b_hh,
                       const float* __restrict__ w_hh,
                       float* __restrict__ h, float* __restrict__ c) {
  int s = blockIdx.x;
  int tid = threadIdx.x;
  __shared__ float zs[KND], inter[KH], h0[KH], c0[KH], g[4*KH];
  if (tid < KND) zs[tid] = z[s*KND + tid];
  __syncthreads();
  if (tid < KH) {
    float a = l1b[tid];
#pragma unroll
    for (int k = 0; k < KND; ++k) a = fmaf(zs[k], l1w[k*KH + tid], a);
    inter[tid] = tanhf(a);
  }
  __syncthreads();
  if (tid < KH) {
    float a2 = l2b[tid], a3 = l3b[tid];
#pragma unroll
    for (int k = 0; k < KH; ++k) {
      float iv = inter[k];
      a2 = fmaf(iv, l2w[k*KH + tid], a2);
      a3 = fmaf(iv, l3w[k*KH + tid], a3);
    }
    h0[tid] = tanhf(a2);
    c0[tid] = tanhf(a3);
  }
  __syncthreads();
  if (tid < 4*KH) {
    float a = b_ih[tid] + b_hh[tid];          // x0 = 0 -> no w_ih term
#pragma unroll 8
    for (int k = 0; k < KH; ++k) a = fmaf(h0[k], w_hh[k*4*KH + tid], a);
    g[tid] = a;
  }
  __syncthreads();
  if (tid < KH) {
    float gi = g[tid], gf = g[KH+tid], gg = g[2*KH+tid], go = g[3*KH+tid];
    float cn = sigmoidf_(gf) * c0[tid] + sigmoidf_(gi) * tanhf(gg);
    float hn = sigmoidf_(go) * tanhf(cn);
    h[s*KH + tid] = hn;
    c[s*KH + tid] = cn;
  }
}

// ------- per-step: reduce prev partial argmax -> idx, gather x=W_down[idx], LSTM cell -------
__global__ void k_step(const unsigned long long* __restrict__ pp,
                       int* __restrict__ idx_out,
                       const float* __restrict__ W_down,
                       const float* __restrict__ w_ih, const float* __restrict__ w_hh,
                       const float* __restrict__ b_ih, const float* __restrict__ b_hh,
                       float* __restrict__ h, float* __restrict__ c) {
  int s = blockIdx.x;
  int tid = threadIdx.x;
  __shared__ unsigned long long sp[256];
  __shared__ float xs[KDW], hs[KH], g[4*KH];
  unsigned long long p = 0ull;
  if (tid < KNCH) p = pp[(size_t)s*KNCH + tid];
  if (tid + 256 < KNCH) {
    unsigned long long q = pp[(size_t)s*KNCH + tid + 256];
    if (q > p) p = q;
  }
  sp[tid] = p;
  __syncthreads();
  for (int off = 128; off > 0; off >>= 1) {
    if (tid < off) {
      unsigned long long q = sp[tid+off];
      if (q > sp[tid]) sp[tid] = q;
    }
    __syncthreads();
  }
  int widx = (int)(~(unsigned)(sp[0] & 0xFFFFFFFFull));
  if (tid == 0) idx_out[s] = widx;
  if (tid < KDW) xs[tid] = W_down[(size_t)widx*KDW + tid];
  if (tid >= KDW && tid < KDW + KH) hs[tid - KDW] = h[s*KH + (tid - KDW)];
  __syncthreads();
  if (tid < 4*KH) {
    float a = b_ih[tid] + b_hh[tid];
#pragma unroll 8
    for (int k = 0; k < KDW; ++k) a = fmaf(xs[k], w_ih[k*4*KH + tid], a);
#pragma unroll 8
    for (int k = 0; k < KH; ++k) a = fmaf(hs[k], w_hh[k*4*KH + tid], a);
    g[tid] = a;
  }
  __syncthreads();
  if (tid < KH) {
    float gi = g[tid], gf = g[KH+tid], gg2 = g[2*KH+tid], go = g[3*KH+tid];
    float cold = c[s*KH + tid];
    float cn = sigmoidf_(gf) * cold + sigmoidf_(gi) * tanhf(gg2);
    float hn = sigmoidf_(go) * tanhf(cn);
    h[s*KH + tid] = hn;
    c[s*KH + tid] = cn;
  }
}

// ------- big kernel: partial argmax over score = h.Wup_col + b_up + gumbel(u);
//         fused one-hot write of the PREVIOUS step's output -------
// wave -> 8 samples x 64 cols; ALL u loads issued up-front (8 deep);
// one-hot write via float4 stores; wA[40] only -> ~80 VGPR, 5 waves/SIMD.
__global__ void __launch_bounds__(256, 5) k_argmax(
    const float* __restrict__ u_t,          // gumbel_u + t*NS*N
    const float* __restrict__ h,            // [NS][KH]
    const float* __restrict__ W_up,         // [KH][KN]
    const float* __restrict__ b_up,         // [KN]
    unsigned long long* __restrict__ pp,    // [NS][KNCH] packed partials
    const int* __restrict__ idx_prev,       // [NS] (valid iff write_prev)
    float* __restrict__ out_prev,           // out + (t-1)*KN (valid iff write_prev)
    int write_prev) {
  int ch   = blockIdx.x;          // 0..312, 64 cols each
  int sg   = blockIdx.y;          // 0..15, 32 samples each
  int tid  = threadIdx.x;
  int wave = tid >> 6, lane = tid & 63;
  int s0   = __builtin_amdgcn_readfirstlane(sg*32 + wave*8);  // 8 samples per wave
  int n0   = ch*64;

  int cA = n0 + lane;
  bool vA = cA < KN;
  int cAc = vA ? cA : 0;

  // --- one-hot write of previous step, float4 stores (drain during compute) ---
  if (write_prev) {
    int r  = lane >> 4;            // 0..3
    int cq = (lane & 15) * 4;      // 0,4,...,60
    if (n0 + cq + 3 < KN) {        // tail chunk: only cq<32 valid (KN%64==32)
#pragma unroll
      for (int pass = 0; pass < 2; ++pass) {
        int s = s0 + pass*4 + r;
        int target = idx_prev[s];
        int cb = n0 + cq;
        float4 v;
        v.x = (cb     == target) ? 1.0f : 0.0f;
        v.y = (cb + 1 == target) ? 1.0f : 0.0f;
        v.z = (cb + 2 == target) ? 1.0f : 0.0f;
        v.w = (cb + 3 == target) ? 1.0f : 0.0f;
        *reinterpret_cast<float4*>(out_prev + (size_t)s*(KRW*KN) + cb) = v;
      }
    }
  }

  // --- issue ALL 8 u loads up-front (8 outstanding per wave) ---
  float uu[8];
  {
    const float* up = u_t + (size_t)s0 * KN + cAc;
#pragma unroll
    for (int ss = 0; ss < 8; ++ss) { uu[ss] = *up; up += KN; }
  }

  // --- W_up column in registers (64 cols per wave -> 40 VGPRs) ---
  float wA[KH];
#pragma unroll
  for (int k = 0; k < KH; ++k) wA[k] = W_up[k*KN + cAc];
  float bA = b_up[cAc];

  // --- main loop: 8 samples ---
  unsigned long long p[8];
  const float* hr = h + s0*KH;                 // wave-uniform -> scalar loads
#pragma unroll
  for (int ss = 0; ss < 8; ++ss) {
    float tA = fmaf(-KLN2, __log2f(uu[ss] + KEPS), KEPS);   // -ln(u+eps)+eps
    float gA = -KLN2 * __log2f(tA);                          // -ln(.)
    float scA = bA + gA;
#pragma unroll
    for (int k = 0; k < KH; ++k) scA = fmaf(hr[k], wA[k], scA);
    p[ss] = vA ? packsc_(scA, cA) : 0ull;
    hr += KH;
  }

  // --- batched cross-lane reduce: 8 independent 6-stage chains ---
#pragma unroll
  for (int d = 32; d > 0; d >>= 1) {
#pragma unroll
    for (int ss = 0; ss < 8; ++ss) {
      unsigned long long q = (unsigned long long)__shfl_xor((long long)p[ss], d, 64);
      if (q > p[ss]) p[ss] = q;
    }
  }
  if (lane == 0) {
#pragma unroll
    for (int ss = 0; ss < 8; ++ss) pp[(size_t)(s0+ss)*KNCH + ch] = p[ss];
  }
}

// ------- final reduce for step 7, fused with its one-hot write -------
__global__ void k_reduce_write(const unsigned long long* __restrict__ pp,
                               float* __restrict__ out) {
  int s = blockIdx.x;
  int tid = threadIdx.x;
  __shared__ unsigned long long sp[256];
  unsigned long long p = 0ull;
  if (tid < KNCH) p = pp[(size_t)s*KNCH + tid];
  if (tid + 256 < KNCH) {
    unsigned long long q = pp[(size_t)s*KNCH + tid + 256];
    if (q > p) p = q;
  }
  sp[tid] = p;
  __syncthreads();
  for (int off = 128; off > 0; off >>= 1) {
    if (tid < off) {
      unsigned long long q = sp[tid+off];
      if (q > sp[tid]) sp[tid] = q;
    }
    __syncthreads();
  }
  int widx = (int)(~(unsigned)(sp[0] & 0xFFFFFFFFull));
  // write one-hot row for step 7: KN/4 = 5000 float4s across 256 threads
  float4* row = (float4*)(out + (size_t)s*(KRW*KN) + (size_t)7*KN);
  for (int j = tid; j < KN/4; j += 256) {
    float4 v = make_float4(0.f, 0.f, 0.f, 0.f);
    int base = j*4;
    if (widx - base >= 0 && widx - base < 4) {
      if (widx - base == 0) v.x = 1.f;
      else if (widx - base == 1) v.y = 1.f;
      else if (widx - base == 2) v.z = 1.f;
      else v.w = 1.f;
    }
    row[j] = v;
  }
}

extern "C" void kernel_launch(void* const* d_in, const int* in_sizes, int n_in,
                              void* d_out, int out_size, void* d_ws, size_t ws_size,
                              hipStream_t stream) {
  const float* z      = (const float*)d_in[0];
  const float* gu     = (const float*)d_in[1];
  const float* l1w    = (const float*)d_in[2];
  const float* l1b    = (const float*)d_in[3];
  const float* l2w    = (const float*)d_in[4];
  const float* l2b    = (const float*)d_in[5];
  const float* l3w    = (const float*)d_in[6];
  const float* l3b    = (const float*)d_in[7];
  const float* w_ih   = (const float*)d_in[8];
  const float* w_hh   = (const float*)d_in[9];
  const float* b_ih   = (const float*)d_in[10];
  const float* b_hh   = (const float*)d_in[11];
  const float* W_up   = (const float*)d_in[12];
  const float* b_up   = (const float*)d_in[13];
  const float* W_down = (const float*)d_in[14];
  float* out = (float*)d_out;

  // workspace layout (~1.47 MB)
  char* ws = (char*)d_ws;
  float* h  = (float*)(ws);                                    // 512*40 f32
  float* c  = (float*)(ws + (size_t)KNS*KH*4);                 // 512*40 f32
  unsigned long long* pp = (unsigned long long*)(ws + (size_t)2*KNS*KH*4);  // 512*313 u64
  int* idx  = (int*)(ws + (size_t)2*KNS*KH*4 + (size_t)KNS*KNCH*8);         // 8*512 i32

  k_init<<<KNS, 256, 0, stream>>>(z, l1w, l1b, l2w, l2b, l3w, l3b, b_ih, b_hh, w_hh, h, c);

  for (int t = 0; t < KRW; ++t) {
    if (t > 0) {
      k_step<<<KNS, 256, 0, stream>>>(pp, idx + (t-1)*KNS, W_down,
                                      w_ih, w_hh, b_ih, b_hh, h, c);
    }
    k_argmax<<<dim3(KNCH, 16), 256, 0, stream>>>(
        gu + (size_t)t*KNS*KN, h, W_up, b_up, pp,
        idx + (t > 0 ? (t-1)*KNS : 0),
        out + (t > 0 ? (size_t)(t-1)*KN : 0),
        t > 0 ? 1 : 0);
  }
  k_reduce_write<<<KNS, 256, 0, stream>>>(pp, out);
}

// Round 5
// 389.928 us; speedup vs baseline: 1.4723x; 1.4723x over previous
//
#include <hip/hip_runtime.h>
#include <math.h>

// Problem constants (from reference)
#define KN    20000   // vocab
#define KH    40      // LSTM hidden
#define KDW   128     // W_down width
#define KND   16      // noise dim
#define KRW   8       // rw_len
#define KNS   512     // n_sample
#define KNCH  313     // ceil(KN / 64) wave-chunks of 64 cols
#define KEPS  1e-20f
#define KLN2  0.69314718055994531f

typedef float floatx4 __attribute__((ext_vector_type(4)));

__device__ __forceinline__ float sigmoidf_(float x) { return 1.0f / (1.0f + expf(-x)); }

// pack (score, col) into a monotone-increasing u64 key; larger = better.
// ties on score -> smaller col wins (low field = ~col).
__device__ __forceinline__ unsigned long long packsc_(float v, int col) {
  unsigned u = __float_as_uint(v);
  unsigned key = (u >> 31) ? ~u : (u | 0x80000000u);
  return ((unsigned long long)key << 32) | (unsigned)(~col);
}

// ---------------- init: 3-layer MLP (h0,c0) + LSTM step 0 (x=0) ----------------
__global__ void k_init(const float* __restrict__ z,
                       const float* __restrict__ l1w, const float* __restrict__ l1b,
                       const float* __restrict__ l2w, const float* __restrict__ l2b,
                       const float* __restrict__ l3w, const float* __restrict__ l3b,
                       const float* __restrict__ b_ih, const float* __restrict__ b_hh,
                       const float* __restrict__ w_hh,
                       float* __restrict__ h, float* __restrict__ c) {
  int s = blockIdx.x;
  int tid = threadIdx.x;
  __shared__ float zs[KND], inter[KH], h0[KH], c0[KH], g[4*KH];
  if (tid < KND) zs[tid] = z[s*KND + tid];
  __syncthreads();
  if (tid < KH) {
    float a = l1b[tid];
#pragma unroll
    for (int k = 0; k < KND; ++k) a = fmaf(zs[k], l1w[k*KH + tid], a);
    inter[tid] = tanhf(a);
  }
  __syncthreads();
  if (tid < KH) {
    float a2 = l2b[tid], a3 = l3b[tid];
#pragma unroll
    for (int k = 0; k < KH; ++k) {
      float iv = inter[k];
      a2 = fmaf(iv, l2w[k*KH + tid], a2);
      a3 = fmaf(iv, l3w[k*KH + tid], a3);
    }
    h0[tid] = tanhf(a2);
    c0[tid] = tanhf(a3);
  }
  __syncthreads();
  if (tid < 4*KH) {
    float a = b_ih[tid] + b_hh[tid];          // x0 = 0 -> no w_ih term
#pragma unroll 8
    for (int k = 0; k < KH; ++k) a = fmaf(h0[k], w_hh[k*4*KH + tid], a);
    g[tid] = a;
  }
  __syncthreads();
  if (tid < KH) {
    float gi = g[tid], gf = g[KH+tid], gg = g[2*KH+tid], go = g[3*KH+tid];
    float cn = sigmoidf_(gf) * c0[tid] + sigmoidf_(gi) * tanhf(gg);
    float hn = sigmoidf_(go) * tanhf(cn);
    h[s*KH + tid] = hn;
    c[s*KH + tid] = cn;
  }
}

// ------- per-step: reduce prev partial argmax -> idx, gather x=W_down[idx], LSTM cell -------
__global__ void k_step(const unsigned long long* __restrict__ pp,
                       int* __restrict__ idx_out,
                       const float* __restrict__ W_down,
                       const float* __restrict__ w_ih, const float* __restrict__ w_hh,
                       const float* __restrict__ b_ih, const float* __restrict__ b_hh,
                       float* __restrict__ h, float* __restrict__ c) {
  int s = blockIdx.x;
  int tid = threadIdx.x;
  __shared__ unsigned long long sp[256];
  __shared__ float xs[KDW], hs[KH], g[4*KH];
  unsigned long long p = 0ull;
  if (tid < KNCH) p = pp[(size_t)s*KNCH + tid];
  if (tid + 256 < KNCH) {
    unsigned long long q = pp[(size_t)s*KNCH + tid + 256];
    if (q > p) p = q;
  }
  sp[tid] = p;
  __syncthreads();
  for (int off = 128; off > 0; off >>= 1) {
    if (tid < off) {
      unsigned long long q = sp[tid+off];
      if (q > sp[tid]) sp[tid] = q;
    }
    __syncthreads();
  }
  int widx = (int)(~(unsigned)(sp[0] & 0xFFFFFFFFull));
  if (tid == 0) idx_out[s] = widx;
  if (tid < KDW) xs[tid] = W_down[(size_t)widx*KDW + tid];
  if (tid >= KDW && tid < KDW + KH) hs[tid - KDW] = h[s*KH + (tid - KDW)];
  __syncthreads();
  if (tid < 4*KH) {
    float a = b_ih[tid] + b_hh[tid];
#pragma unroll 8
    for (int k = 0; k < KDW; ++k) a = fmaf(xs[k], w_ih[k*4*KH + tid], a);
#pragma unroll 8
    for (int k = 0; k < KH; ++k) a = fmaf(hs[k], w_hh[k*4*KH + tid], a);
    g[tid] = a;
  }
  __syncthreads();
  if (tid < KH) {
    float gi = g[tid], gf = g[KH+tid], gg2 = g[2*KH+tid], go = g[3*KH+tid];
    float cold = c[s*KH + tid];
    float cn = sigmoidf_(gf) * cold + sigmoidf_(gi) * tanhf(gg2);
    float hn = sigmoidf_(go) * tanhf(cn);
    h[s*KH + tid] = hn;
    c[s*KH + tid] = cn;
  }
}

// ------- big kernel: partial argmax over score = h.Wup_col + b_up + gumbel(u);
//         fused one-hot write of the PREVIOUS step's output -------
// wave -> 8 samples x 64 cols; ALL 8 u loads issued up-front (nontemporal);
// wA[40] only -> ~80-95 VGPR at (256,4) cap 128: no spills, 5-6 waves/SIMD natural.
__global__ void __launch_bounds__(256, 4) k_argmax(
    const float* __restrict__ u_t,          // gumbel_u + t*NS*N
    const float* __restrict__ h,            // [NS][KH]
    const float* __restrict__ W_up,         // [KH][KN]
    const float* __restrict__ b_up,         // [KN]
    unsigned long long* __restrict__ pp,    // [NS][KNCH] packed partials
    const int* __restrict__ idx_prev,       // [NS] (valid iff write_prev)
    float* __restrict__ out_prev,           // out + (t-1)*KN (valid iff write_prev)
    int write_prev) {
  int ch   = blockIdx.x;          // 0..312, 64 cols each
  int sg   = blockIdx.y;          // 0..15, 32 samples each
  int tid  = threadIdx.x;
  int wave = tid >> 6, lane = tid & 63;
  int s0   = __builtin_amdgcn_readfirstlane(sg*32 + wave*8);  // 8 samples per wave
  int n0   = ch*64;

  int cA = n0 + lane;
  bool vA = cA < KN;
  int cAc = vA ? cA : 0;

  // --- issue ALL 8 u loads up-front (8 outstanding, nontemporal: stream-once) ---
  float uu[8];
  {
    const float* up = u_t + (size_t)s0 * KN + cAc;
#pragma unroll
    for (int ss = 0; ss < 8; ++ss) { uu[ss] = __builtin_nontemporal_load(up); up += KN; }
  }

  // --- W_up column in registers (64 cols per wave -> 40 VGPRs); keep in L2 ---
  float wA[KH];
#pragma unroll
  for (int k = 0; k < KH; ++k) wA[k] = W_up[k*KN + cAc];
  float bA = b_up[cAc];

  // --- one-hot write of previous step (stores drain while we compute) ---
  if (write_prev) {
    float* op = out_prev + (size_t)s0 * (KRW*KN) + cA;
#pragma unroll
    for (int ss = 0; ss < 8; ++ss) {
      int target = idx_prev[s0 + ss];      // uniform -> s_load
      if (vA) __builtin_nontemporal_store((cA == target) ? 1.0f : 0.0f, op);
      op += KRW*KN;
    }
  }

  // --- main loop: 8 samples ---
  unsigned long long p[8];
  const float* hr = h + s0*KH;                 // wave-uniform -> scalar loads
#pragma unroll
  for (int ss = 0; ss < 8; ++ss) {
    float tA = fmaf(-KLN2, __log2f(uu[ss] + KEPS), KEPS);   // -ln(u+eps)+eps
    float gA = -KLN2 * __log2f(tA);                          // -ln(.)
    float scA = bA + gA;
#pragma unroll
    for (int k = 0; k < KH; ++k) scA = fmaf(hr[k], wA[k], scA);
    p[ss] = vA ? packsc_(scA, cA) : 0ull;
    hr += KH;
  }

  // --- batched cross-lane reduce: 8 independent 6-stage chains ---
#pragma unroll
  for (int d = 32; d > 0; d >>= 1) {
#pragma unroll
    for (int ss = 0; ss < 8; ++ss) {
      unsigned long long q = (unsigned long long)__shfl_xor((long long)p[ss], d, 64);
      if (q > p[ss]) p[ss] = q;
    }
  }
  if (lane == 0) {
#pragma unroll
    for (int ss = 0; ss < 8; ++ss) pp[(size_t)(s0+ss)*KNCH + ch] = p[ss];
  }
}

// ------- final reduce for step 7, fused with its one-hot write -------
__global__ void k_reduce_write(const unsigned long long* __restrict__ pp,
                               float* __restrict__ out) {
  int s = blockIdx.x;
  int tid = threadIdx.x;
  __shared__ unsigned long long sp[256];
  unsigned long long p = 0ull;
  if (tid < KNCH) p = pp[(size_t)s*KNCH + tid];
  if (tid + 256 < KNCH) {
    unsigned long long q = pp[(size_t)s*KNCH + tid + 256];
    if (q > p) p = q;
  }
  sp[tid] = p;
  __syncthreads();
  for (int off = 128; off > 0; off >>= 1) {
    if (tid < off) {
      unsigned long long q = sp[tid+off];
      if (q > sp[tid]) sp[tid] = q;
    }
    __syncthreads();
  }
  int widx = (int)(~(unsigned)(sp[0] & 0xFFFFFFFFull));
  // write one-hot row for step 7: KN/4 = 5000 float4s across 256 threads
  floatx4* row = (floatx4*)(out + (size_t)s*(KRW*KN) + (size_t)7*KN);
  for (int j = tid; j < KN/4; j += 256) {
    floatx4 v = (floatx4)(0.f);
    int base = j*4;
    int d = widx - base;
    if (d >= 0 && d < 4) v[d] = 1.f;
    __builtin_nontemporal_store(v, row + j);
  }
}

extern "C" void kernel_launch(void* const* d_in, const int* in_sizes, int n_in,
                              void* d_out, int out_size, void* d_ws, size_t ws_size,
                              hipStream_t stream) {
  const float* z      = (const float*)d_in[0];
  const float* gu     = (const float*)d_in[1];
  const float* l1w    = (const float*)d_in[2];
  const float* l1b    = (const float*)d_in[3];
  const float* l2w    = (const float*)d_in[4];
  const float* l2b    = (const float*)d_in[5];
  const float* l3w    = (const float*)d_in[6];
  const float* l3b    = (const float*)d_in[7];
  const float* w_ih   = (const float*)d_in[8];
  const float* w_hh   = (const float*)d_in[9];
  const float* b_ih   = (const float*)d_in[10];
  const float* b_hh   = (const float*)d_in[11];
  const float* W_up   = (const float*)d_in[12];
  const float* b_up   = (const float*)d_in[13];
  const float* W_down = (const float*)d_in[14];
  float* out = (float*)d_out;

  // workspace layout (~1.47 MB)
  char* ws = (char*)d_ws;
  float* h  = (float*)(ws);                                    // 512*40 f32
  float* c  = (float*)(ws + (size_t)KNS*KH*4);                 // 512*40 f32
  unsigned long long* pp = (unsigned long long*)(ws + (size_t)2*KNS*KH*4);  // 512*313 u64
  int* idx  = (int*)(ws + (size_t)2*KNS*KH*4 + (size_t)KNS*KNCH*8);         // 8*512 i32

  k_init<<<KNS, 256, 0, stream>>>(z, l1w, l1b, l2w, l2b, l3w, l3b, b_ih, b_hh, w_hh, h, c);

  for (int t = 0; t < KRW; ++t) {
    if (t > 0) {
      k_step<<<KNS, 256, 0, stream>>>(pp, idx + (t-1)*KNS, W_down,
                                      w_ih, w_hh, b_ih, b_hh, h, c);
    }
    k_argmax<<<dim3(KNCH, 16), 256, 0, stream>>>(
        gu + (size_t)t*KNS*KN, h, W_up, b_up, pp,
        idx + (t > 0 ? (t-1)*KNS : 0),
        out + (t > 0 ? (size_t)(t-1)*KN : 0),
        t > 0 ? 1 : 0);
  }
  k_reduce_write<<<KNS, 256, 0, stream>>>(pp, out);
}

// Round 6
// 380.010 us; speedup vs baseline: 1.5107x; 1.0261x over previous
//
#include <hip/hip_runtime.h>
#include <math.h>

// Problem constants (from reference)
#define KN    20000   // vocab
#define KH    40      // LSTM hidden
#define KDW   128     // W_down width
#define KND   16      // noise dim
#define KRW   8       // rw_len
#define KNS   512     // n_sample
#define KNCH  313     // ceil(KN / 64) wave-chunks of 64 cols
#define KEPS  1e-20f
#define KLN2  0.69314718055994531f

typedef float floatx4 __attribute__((ext_vector_type(4)));

__device__ __forceinline__ float sigmoidf_(float x) { return 1.0f / (1.0f + expf(-x)); }

// pack (score, col) into a monotone-increasing u64 key; larger = better.
// ties on score -> smaller col wins (low field = ~col).
__device__ __forceinline__ unsigned long long packsc_(float v, int col) {
  unsigned u = __float_as_uint(v);
  unsigned key = (u >> 31) ? ~u : (u | 0x80000000u);
  return ((unsigned long long)key << 32) | (unsigned)(~col);
}
__device__ __forceinline__ float unpackv_(unsigned long long pk) {
  unsigned key = (unsigned)(pk >> 32);
  unsigned ub = (key & 0x80000000u) ? (key ^ 0x80000000u) : ~key;
  return __uint_as_float(ub);
}
// Gumbel(0,1) from uniform u — identical op DAG everywhere it's used.
__device__ __forceinline__ float gumbel_(float u) {
  float t = fmaf(-KLN2, __log2f(u + KEPS), KEPS);   // -ln(u+eps)+eps
  return -KLN2 * __log2f(t);                         // -ln(.)
}

// ---------------- one-time: wnmax = max_j ||W_up[:,j]||_2 ----------------
__global__ void k_wnorm(const float* __restrict__ W_up, float* __restrict__ wnmax) {
  int j = blockIdx.x * 256 + threadIdx.x;
  int lane = threadIdx.x & 63;
  float ss = 0.f;
  if (j < KN) {
#pragma unroll
    for (int k = 0; k < KH; ++k) { float w = W_up[k*KN + j]; ss = fmaf(w, w, ss); }
  }
  float wn = sqrtf(ss);
#pragma unroll
  for (int d = 32; d > 0; d >>= 1) wn = fmaxf(wn, __shfl_xor(wn, d, 64));
  if (lane == 0) atomicMax((int*)wnmax, __float_as_int(wn));  // all positive -> int cmp ok
}

// ---------------- init: 3-layer MLP (h0,c0) + LSTM step 0 (x=0); writes hnorm ----------------
__global__ void k_init(const float* __restrict__ z,
                       const float* __restrict__ l1w, const float* __restrict__ l1b,
                       const float* __restrict__ l2w, const float* __restrict__ l2b,
                       const float* __restrict__ l3w, const float* __restrict__ l3b,
                       const float* __restrict__ b_ih, const float* __restrict__ b_hh,
                       const float* __restrict__ w_hh,
                       float* __restrict__ h, float* __restrict__ c,
                       float* __restrict__ hnorm) {
  int s = blockIdx.x;
  int tid = threadIdx.x;
  __shared__ float zs[KND], inter[KH], h0[KH], c0[KH], g[4*KH], hn2[KH];
  if (tid < KND) zs[tid] = z[s*KND + tid];
  __syncthreads();
  if (tid < KH) {
    float a = l1b[tid];
#pragma unroll
    for (int k = 0; k < KND; ++k) a = fmaf(zs[k], l1w[k*KH + tid], a);
    inter[tid] = tanhf(a);
  }
  __syncthreads();
  if (tid < KH) {
    float a2 = l2b[tid], a3 = l3b[tid];
#pragma unroll
    for (int k = 0; k < KH; ++k) {
      float iv = inter[k];
      a2 = fmaf(iv, l2w[k*KH + tid], a2);
      a3 = fmaf(iv, l3w[k*KH + tid], a3);
    }
    h0[tid] = tanhf(a2);
    c0[tid] = tanhf(a3);
  }
  __syncthreads();
  if (tid < 4*KH) {
    float a = b_ih[tid] + b_hh[tid];          // x0 = 0 -> no w_ih term
#pragma unroll 8
    for (int k = 0; k < KH; ++k) a = fmaf(h0[k], w_hh[k*4*KH + tid], a);
    g[tid] = a;
  }
  __syncthreads();
  if (tid < KH) {
    float gi = g[tid], gf = g[KH+tid], gg = g[2*KH+tid], go = g[3*KH+tid];
    float cn = sigmoidf_(gf) * c0[tid] + sigmoidf_(gi) * tanhf(gg);
    float hn = sigmoidf_(go) * tanhf(cn);
    h[s*KH + tid] = hn;
    c[s*KH + tid] = cn;
    hn2[tid] = hn * hn;
  }
  __syncthreads();
  if (tid == 0) {
    float ssum = 0.f;
#pragma unroll
    for (int k = 0; k < KH; ++k) ssum += hn2[k];
    hnorm[s] = sqrtf(ssum);
  }
}

// ------- streaming kernel: key = gumbel(u) + b_up (NO dot product);
//         per-chunk packed max -> pp; fused one-hot write of prev step -------
__global__ void __launch_bounds__(256) k_score(
    const float* __restrict__ u_t,          // gumbel_u + t*NS*N
    const float* __restrict__ b_up,         // [KN]
    unsigned long long* __restrict__ pp,    // [NS][KNCH]
    const int* __restrict__ idx_prev,       // [NS] (valid iff write_prev)
    float* __restrict__ out_prev,           // out + (t-1)*KN (valid iff write_prev)
    int write_prev) {
  int ch   = blockIdx.x;          // 0..312, 64 cols each
  int sg   = blockIdx.y;          // 0..15, 32 samples each
  int tid  = threadIdx.x;
  int wave = tid >> 6, lane = tid & 63;
  int s0   = __builtin_amdgcn_readfirstlane(sg*32 + wave*8);  // 8 samples per wave
  int n0   = ch*64;
  int cA   = n0 + lane;
  bool vA  = cA < KN;
  int cAc  = vA ? cA : 0;

  // issue ALL 8 u loads up-front (nontemporal: stream-once)
  float uu[8];
  {
    const float* up = u_t + (size_t)s0 * KN + cAc;
#pragma unroll
    for (int ss = 0; ss < 8; ++ss) { uu[ss] = __builtin_nontemporal_load(up); up += KN; }
  }
  float bA = b_up[cAc];

  // one-hot write of previous step (stores drain while we compute)
  if (write_prev) {
    float* op = out_prev + (size_t)s0 * (KRW*KN) + cA;
#pragma unroll
    for (int ss = 0; ss < 8; ++ss) {
      int target = idx_prev[s0 + ss];      // uniform -> s_load
      if (vA) __builtin_nontemporal_store((cA == target) ? 1.0f : 0.0f, op);
      op += KRW*KN;
    }
  }

  // cheap keys: g + b (no h.w dot!)
  unsigned long long p[8];
#pragma unroll
  for (int ss = 0; ss < 8; ++ss) {
    float key = gumbel_(uu[ss]) + bA;
    p[ss] = vA ? packsc_(key, cA) : 0ull;
  }

  // batched cross-lane reduce: 8 independent 6-stage chains
#pragma unroll
  for (int d = 32; d > 0; d >>= 1) {
#pragma unroll
    for (int ss = 0; ss < 8; ++ss) {
      unsigned long long q = (unsigned long long)__shfl_xor((long long)p[ss], d, 64);
      if (q > p[ss]) p[ss] = q;
    }
  }
  if (lane == 0) {
#pragma unroll
    for (int ss = 0; ss < 8; ++ss) pp[(size_t)(s0+ss)*KNCH + ch] = p[ss];
  }
}

// ------- per-step: bound-pruned exact argmax resolve + LSTM cell -------
__global__ void __launch_bounds__(256) k_step(
    const unsigned long long* __restrict__ pp,
    const float* __restrict__ u_prev,       // gumbel_u + (t-1)*NS*N
    const float* __restrict__ W_up, const float* __restrict__ b_up,
    const float* __restrict__ wnmax,
    float* __restrict__ hnorm,
    int* __restrict__ idx_out,
    const float* __restrict__ W_down,
    const float* __restrict__ w_ih, const float* __restrict__ w_hh,
    const float* __restrict__ b_ih, const float* __restrict__ b_hh,
    float* __restrict__ h, float* __restrict__ c) {
  int s = blockIdx.x, tid = threadIdx.x;
  int wave = tid >> 6, lane = tid & 63;
  __shared__ unsigned long long sp[256];
  __shared__ unsigned long long wmax[4];
  __shared__ int cand[KNCH + 7];
  __shared__ int ncand;
  __shared__ float hs[KH], xs[KDW], g[4*KH], hn2[KH];

  unsigned long long p0 = 0ull, p1 = 0ull;
  if (tid < KNCH) p0 = pp[(size_t)s*KNCH + tid];
  if (tid + 256 < KNCH) p1 = pp[(size_t)s*KNCH + tid + 256];
  unsigned long long pm = p0 > p1 ? p0 : p1;
  sp[tid] = pm;
  if (tid < KH) hs[tid] = h[s*KH + tid];
  if (tid == 0) ncand = 0;
  if (tid < 4) wmax[tid] = 0ull;
  __syncthreads();
  for (int off = 128; off > 0; off >>= 1) {
    if (tid < off) { unsigned long long q = sp[tid+off]; if (q > sp[tid]) sp[tid] = q; }
    __syncthreads();
  }
  float t1v = unpackv_(sp[0]);
  float hwb = hnorm[s] * wnmax[0] * 1.001f + 1e-4f;   // safe |h.w_j| bound
  float thr = t1v - 2.0f*hwb;
  unsigned long long pthr = packsc_(thr, 0x7fffffff);
  if (tid < KNCH && p0 >= pthr)       { int i = atomicAdd(&ncand, 1); cand[i] = tid; }
  if (tid + 256 < KNCH && p1 >= pthr) { int i = atomicAdd(&ncand, 1); cand[i] = tid + 256; }
  __syncthreads();
  int nc = ncand;                       // usually 1-3
  unsigned long long best = 0ull;
  for (int ci = wave; ci < nc; ci += 4) {
    int col = cand[ci]*64 + lane;
    unsigned long long pk = 0ull;
    if (col < KN) {
      float u = u_prev[(size_t)s*KN + col];
      float key = gumbel_(u) + b_up[col];           // identical DAG to k_score
      if (packsc_(key, col) >= pthr) {
        float sc = key;                              // exact score, same fma chain as before
#pragma unroll
        for (int k = 0; k < KH; ++k) sc = fmaf(hs[k], W_up[k*KN + col], sc);
        pk = packsc_(sc, col);
      }
    }
#pragma unroll
    for (int d = 32; d > 0; d >>= 1) {
      unsigned long long q = (unsigned long long)__shfl_xor((long long)pk, d, 64);
      if (q > pk) pk = q;
    }
    if (pk > best) best = pk;
  }
  if (lane == 0) wmax[wave] = best;
  __syncthreads();
  unsigned long long fb = wmax[0];
  if (wmax[1] > fb) fb = wmax[1];
  if (wmax[2] > fb) fb = wmax[2];
  if (wmax[3] > fb) fb = wmax[3];
  int widx = (int)(~(unsigned)(fb & 0xFFFFFFFFull));
  if (tid == 0) idx_out[s] = widx;

  // ---- LSTM cell ----
  if (tid < KDW) xs[tid] = W_down[(size_t)widx*KDW + tid];
  __syncthreads();
  if (tid < 4*KH) {
    float a = b_ih[tid] + b_hh[tid];
#pragma unroll 8
    for (int k = 0; k < KDW; ++k) a = fmaf(xs[k], w_ih[k*4*KH + tid], a);
#pragma unroll 8
    for (int k = 0; k < KH; ++k) a = fmaf(hs[k], w_hh[k*4*KH + tid], a);
    g[tid] = a;
  }
  __syncthreads();
  if (tid < KH) {
    float gi = g[tid], gf = g[KH+tid], gg2 = g[2*KH+tid], go = g[3*KH+tid];
    float cold = c[s*KH + tid];
    float cn = sigmoidf_(gf) * cold + sigmoidf_(gi) * tanhf(gg2);
    float hn = sigmoidf_(go) * tanhf(cn);
    h[s*KH + tid] = hn;
    c[s*KH + tid] = cn;
    hn2[tid] = hn * hn;
  }
  __syncthreads();
  if (tid == 0) {
    float ssum = 0.f;
#pragma unroll
    for (int k = 0; k < KH; ++k) ssum += hn2[k];
    hnorm[s] = sqrtf(ssum);
  }
}

// ------- final: resolve step-7 argmax (same pruning) + write its one-hot row -------
__global__ void __launch_bounds__(256) k_finish(
    const unsigned long long* __restrict__ pp,
    const float* __restrict__ u_prev,       // gumbel_u + 7*NS*N
    const float* __restrict__ W_up, const float* __restrict__ b_up,
    const float* __restrict__ wnmax,
    const float* __restrict__ hnorm,
    const float* __restrict__ h,
    float* __restrict__ out) {
  int s = blockIdx.x, tid = threadIdx.x;
  int wave = tid >> 6, lane = tid & 63;
  __shared__ unsigned long long sp[256];
  __shared__ unsigned long long wmax[4];
  __shared__ int cand[KNCH + 7];
  __shared__ int ncand;
  __shared__ float hs[KH];

  unsigned long long p0 = 0ull, p1 = 0ull;
  if (tid < KNCH) p0 = pp[(size_t)s*KNCH + tid];
  if (tid + 256 < KNCH) p1 = pp[(size_t)s*KNCH + tid + 256];
  unsigned long long pm = p0 > p1 ? p0 : p1;
  sp[tid] = pm;
  if (tid < KH) hs[tid] = h[s*KH + tid];
  if (tid == 0) ncand = 0;
  if (tid < 4) wmax[tid] = 0ull;
  __syncthreads();
  for (int off = 128; off > 0; off >>= 1) {
    if (tid < off) { unsigned long long q = sp[tid+off]; if (q > sp[tid]) sp[tid] = q; }
    __syncthreads();
  }
  float t1v = unpackv_(sp[0]);
  float hwb = hnorm[s] * wnmax[0] * 1.001f + 1e-4f;
  float thr = t1v - 2.0f*hwb;
  unsigned long long pthr = packsc_(thr, 0x7fffffff);
  if (tid < KNCH && p0 >= pthr)       { int i = atomicAdd(&ncand, 1); cand[i] = tid; }
  if (tid + 256 < KNCH && p1 >= pthr) { int i = atomicAdd(&ncand, 1); cand[i] = tid + 256; }
  __syncthreads();
  int nc = ncand;
  unsigned long long best = 0ull;
  for (int ci = wave; ci < nc; ci += 4) {
    int col = cand[ci]*64 + lane;
    unsigned long long pk = 0ull;
    if (col < KN) {
      float u = u_prev[(size_t)s*KN + col];
      float key = gumbel_(u) + b_up[col];
      if (packsc_(key, col) >= pthr) {
        float sc = key;
#pragma unroll
        for (int k = 0; k < KH; ++k) sc = fmaf(hs[k], W_up[k*KN + col], sc);
        pk = packsc_(sc, col);
      }
    }
#pragma unroll
    for (int d = 32; d > 0; d >>= 1) {
      unsigned long long q = (unsigned long long)__shfl_xor((long long)pk, d, 64);
      if (q > pk) pk = q;
    }
    if (pk > best) best = pk;
  }
  if (lane == 0) wmax[wave] = best;
  __syncthreads();
  unsigned long long fb = wmax[0];
  if (wmax[1] > fb) fb = wmax[1];
  if (wmax[2] > fb) fb = wmax[2];
  if (wmax[3] > fb) fb = wmax[3];
  int widx = (int)(~(unsigned)(fb & 0xFFFFFFFFull));

  // one-hot row for step 7
  floatx4* row = (floatx4*)(out + (size_t)s*(KRW*KN) + (size_t)7*KN);
  for (int j = tid; j < KN/4; j += 256) {
    floatx4 v = (floatx4)(0.f);
    int d = widx - j*4;
    if (d >= 0 && d < 4) v[d] = 1.f;
    __builtin_nontemporal_store(v, row + j);
  }
}

extern "C" void kernel_launch(void* const* d_in, const int* in_sizes, int n_in,
                              void* d_out, int out_size, void* d_ws, size_t ws_size,
                              hipStream_t stream) {
  const float* z      = (const float*)d_in[0];
  const float* gu     = (const float*)d_in[1];
  const float* l1w    = (const float*)d_in[2];
  const float* l1b    = (const float*)d_in[3];
  const float* l2w    = (const float*)d_in[4];
  const float* l2b    = (const float*)d_in[5];
  const float* l3w    = (const float*)d_in[6];
  const float* l3b    = (const float*)d_in[7];
  const float* w_ih   = (const float*)d_in[8];
  const float* w_hh   = (const float*)d_in[9];
  const float* b_ih   = (const float*)d_in[10];
  const float* b_hh   = (const float*)d_in[11];
  const float* W_up   = (const float*)d_in[12];
  const float* b_up   = (const float*)d_in[13];
  const float* W_down = (const float*)d_in[14];
  float* out = (float*)d_out;

  // workspace layout (~1.47 MB)
  char* ws = (char*)d_ws;
  float* h  = (float*)(ws);                                     // 512*40 f32
  float* c  = (float*)(ws + (size_t)KNS*KH*4);                  // 512*40 f32
  unsigned long long* pp = (unsigned long long*)(ws + (size_t)2*KNS*KH*4);        // 512*313 u64
  int*   idx   = (int*)  (ws + (size_t)2*KNS*KH*4 + (size_t)KNS*KNCH*8);          // 8*512 i32
  float* hnorm = (float*)(ws + (size_t)2*KNS*KH*4 + (size_t)KNS*KNCH*8 + (size_t)KRW*KNS*4);  // 512 f32
  float* wnmax = hnorm + KNS;                                   // 1 f32

  hipMemsetAsync(wnmax, 0, 4, stream);
  k_wnorm<<<(KN + 255)/256, 256, 0, stream>>>(W_up, wnmax);
  k_init<<<KNS, 256, 0, stream>>>(z, l1w, l1b, l2w, l2b, l3w, l3b, b_ih, b_hh, w_hh,
                                  h, c, hnorm);

  for (int t = 0; t < KRW; ++t) {
    if (t > 0) {
      k_step<<<KNS, 256, 0, stream>>>(pp, gu + (size_t)(t-1)*KNS*KN, W_up, b_up,
                                      wnmax, hnorm, idx + (t-1)*KNS, W_down,
                                      w_ih, w_hh, b_ih, b_hh, h, c);
    }
    k_score<<<dim3(KNCH, 16), 256, 0, stream>>>(
        gu + (size_t)t*KNS*KN, b_up, pp,
        idx + (t > 0 ? (t-1)*KNS : 0),
        out + (t > 0 ? (size_t)(t-1)*KN : 0),
        t > 0 ? 1 : 0);
  }
  k_finish<<<KNS, 256, 0, stream>>>(pp, gu + (size_t)7*KNS*KN, W_up, b_up,
                                    wnmax, hnorm, h, out);
}

// Round 7
// 269.388 us; speedup vs baseline: 2.1311x; 1.4106x over previous
//
#include <hip/hip_runtime.h>
#include <math.h>

// Problem constants (from reference)
#define KN    20000   // vocab
#define KH    40      // LSTM hidden
#define KDW   128     // W_down width
#define KND   16      // noise dim
#define KRW   8       // rw_len
#define KNS   512     // n_sample
#define KCH   79      // ceil(KN / 256) chunks of 256 cols
#define KEPS  1e-20f
#define KLN2  0.69314718055994531f

typedef float floatx4 __attribute__((ext_vector_type(4)));

__device__ __forceinline__ float sigmoidf_(float x) { return 1.0f / (1.0f + expf(-x)); }

// pack (score, col) into a monotone-increasing u64 key; larger = better.
// ties on score -> smaller col wins (low field = ~col).
__device__ __forceinline__ unsigned long long packsc_(float v, int col) {
  unsigned u = __float_as_uint(v);
  unsigned key = (u >> 31) ? ~u : (u | 0x80000000u);
  return ((unsigned long long)key << 32) | (unsigned)(~col);
}
__device__ __forceinline__ float unpackv_(unsigned long long pk) {
  unsigned key = (unsigned)(pk >> 32);
  unsigned ub = (key & 0x80000000u) ? (key ^ 0x80000000u) : ~key;
  return __uint_as_float(ub);
}
// Gumbel(0,1) from uniform u — identical op DAG everywhere it's used.
__device__ __forceinline__ float gumbel_(float u) {
  float t = fmaf(-KLN2, __log2f(u + KEPS), KEPS);   // -ln(u+eps)+eps
  return -KLN2 * __log2f(t);                         // -ln(.)
}

// ---------------- one-time: wnmax = max_j ||W_up[:,j]||_2 ----------------
__global__ void k_wnorm(const float* __restrict__ W_up, float* __restrict__ wnmax) {
  int j = blockIdx.x * 256 + threadIdx.x;
  int lane = threadIdx.x & 63;
  float ss = 0.f;
  if (j < KN) {
#pragma unroll
    for (int k = 0; k < KH; ++k) { float w = W_up[k*KN + j]; ss = fmaf(w, w, ss); }
  }
  float wn = sqrtf(ss);
#pragma unroll
  for (int d = 32; d > 0; d >>= 1) wn = fmaxf(wn, __shfl_xor(wn, d, 64));
  if (lane == 0) atomicMax((int*)wnmax, __float_as_int(wn));  // all positive -> int cmp ok
}

// ---------------- init: 3-layer MLP (h0,c0) + LSTM step 0 (x=0) ----------------
__global__ void k_init(const float* __restrict__ z,
                       const float* __restrict__ l1w, const float* __restrict__ l1b,
                       const float* __restrict__ l2w, const float* __restrict__ l2b,
                       const float* __restrict__ l3w, const float* __restrict__ l3b,
                       const float* __restrict__ b_ih, const float* __restrict__ b_hh,
                       const float* __restrict__ w_hh,
                       float* __restrict__ h, float* __restrict__ c) {
  int s = blockIdx.x;
  int tid = threadIdx.x;
  __shared__ float zs[KND], inter[KH], h0[KH], c0[KH], g[4*KH];
  if (tid < KND) zs[tid] = z[s*KND + tid];
  __syncthreads();
  if (tid < KH) {
    float a = l1b[tid];
#pragma unroll
    for (int k = 0; k < KND; ++k) a = fmaf(zs[k], l1w[k*KH + tid], a);
    inter[tid] = tanhf(a);
  }
  __syncthreads();
  if (tid < KH) {
    float a2 = l2b[tid], a3 = l3b[tid];
#pragma unroll
    for (int k = 0; k < KH; ++k) {
      float iv = inter[k];
      a2 = fmaf(iv, l2w[k*KH + tid], a2);
      a3 = fmaf(iv, l3w[k*KH + tid], a3);
    }
    h0[tid] = tanhf(a2);
    c0[tid] = tanhf(a3);
  }
  __syncthreads();
  if (tid < 4*KH) {
    float a = b_ih[tid] + b_hh[tid];          // x0 = 0 -> no w_ih term
#pragma unroll 8
    for (int k = 0; k < KH; ++k) a = fmaf(h0[k], w_hh[k*4*KH + tid], a);
    g[tid] = a;
  }
  __syncthreads();
  if (tid < KH) {
    float gi = g[tid], gf = g[KH+tid], gg = g[2*KH+tid], go = g[3*KH+tid];
    float cn = sigmoidf_(gf) * c0[tid] + sigmoidf_(gi) * tanhf(gg);
    float hn = sigmoidf_(go) * tanhf(cn);
    h[s*KH + tid] = hn;
    c[s*KH + tid] = cn;
  }
}

// ------- phase A: ALL timesteps' chunk maxima of key = gumbel(u)+b_up (no h) -------
// grid (KCH, 16, KRW); wave -> 8 samples x 256 cols (4 cols/lane via float4).
__global__ void __launch_bounds__(256) k_score_all(
    const float* __restrict__ gu,           // gumbel_u [RW][NS][KN]
    const float* __restrict__ b_up,         // [KN]
    unsigned long long* __restrict__ pp) {  // [RW][NS][KCH]
  int ch = blockIdx.x, sg = blockIdx.y, t = blockIdx.z;
  int tid = threadIdx.x, wave = tid >> 6, lane = tid & 63;
  int s0 = __builtin_amdgcn_readfirstlane(sg*32 + wave*8);   // 8 samples per wave
  int base = ch*256 + lane*4;
  bool v = base < KN;                  // KN%4==0 -> base<KN implies base+3<KN
  int basec = v ? base : (KN - 4);

  const float* ut = gu + ((size_t)t*KNS + s0)*KN;
  floatx4 uu[8];
#pragma unroll
  for (int ss = 0; ss < 8; ++ss)
    uu[ss] = __builtin_nontemporal_load((const floatx4*)(ut + (size_t)ss*KN + basec));
  floatx4 b4 = *(const floatx4*)(b_up + basec);

  unsigned long long p[8];
#pragma unroll
  for (int ss = 0; ss < 8; ++ss) {
    unsigned long long m = 0ull;
#pragma unroll
    for (int i = 0; i < 4; ++i) {
      float key = gumbel_(uu[ss][i]) + b4[i];
      unsigned long long pk = v ? packsc_(key, base + i) : 0ull;
      if (pk > m) m = pk;
    }
    p[ss] = m;
  }
#pragma unroll
  for (int d = 32; d > 0; d >>= 1) {
#pragma unroll
    for (int ss = 0; ss < 8; ++ss) {
      unsigned long long q = (unsigned long long)__shfl_xor((long long)p[ss], d, 64);
      if (q > p[ss]) p[ss] = q;
    }
  }
  if (lane == 0) {
#pragma unroll
    for (int ss = 0; ss < 8; ++ss)
      pp[((size_t)t*KNS + s0 + ss)*KCH + ch] = p[ss];
  }
}

// ------- phase B: ONE kernel, 512 blocks; block = sample, loops t=0..7:
//         chunk-reduce -> bound-pruned exact rescan -> idx[t], LSTM advance -------
__global__ void __launch_bounds__(256) k_resolve(
    const unsigned long long* __restrict__ pp,
    const float* __restrict__ gu,
    const float* __restrict__ W_up, const float* __restrict__ b_up,
    const float* __restrict__ wnmax,
    const float* __restrict__ hg, const float* __restrict__ cg,
    const float* __restrict__ W_down,
    const float* __restrict__ w_ih, const float* __restrict__ w_hh,
    const float* __restrict__ b_ih, const float* __restrict__ b_hh,
    int* __restrict__ idx) {
  int s = blockIdx.x, tid = threadIdx.x;
  int wave = tid >> 6, lane = tid & 63;
  __shared__ unsigned long long sp[128];
  __shared__ int cand[KCH + 1];
  __shared__ int ncand;
  __shared__ float hs[KH], cs[KH], xs[KDW], g[4*KH];
  __shared__ float hnS;
  __shared__ int widxS;

  if (tid < KH) { hs[tid] = hg[s*KH + tid]; cs[tid] = cg[s*KH + tid]; }
  __syncthreads();
  if (wave == 0) {                       // ||h||
    float x = (lane < KH) ? hs[lane] : 0.f;
    float v = x * x;
#pragma unroll
    for (int d = 32; d > 0; d >>= 1) v += __shfl_xor(v, d, 64);
    if (lane == 0) hnS = sqrtf(v);
  }
  __syncthreads();
  float wnm = wnmax[0];

  for (int t = 0; t < KRW; ++t) {
    // --- chunk-max tree over 79 partials ---
    unsigned long long p0 = 0ull;
    if (tid < KCH) p0 = pp[((size_t)t*KNS + s)*KCH + tid];
    if (tid < 128) sp[tid] = (tid < KCH) ? p0 : 0ull;
    if (tid == 0) ncand = 0;
    __syncthreads();
    for (int off = 64; off > 0; off >>= 1) {
      if (tid < off) { unsigned long long q = sp[tid+off]; if (q > sp[tid]) sp[tid] = q; }
      __syncthreads();
    }
    float t1v = unpackv_(sp[0]);
    float hwb = hnS * wnm * 1.001f + 1e-4f;        // safe |h.w_j| bound
    unsigned long long pthr = packsc_(t1v - 2.0f*hwb, 0x7fffffff);
    if (tid < KCH && p0 >= pthr) { int i = atomicAdd(&ncand, 1); cand[i] = tid; }
    __syncthreads();
    int nc = ncand;                                 // usually 1-2
    unsigned long long best = 0ull;
    const float* urow = gu + ((size_t)t*KNS + s)*KN;
    for (int ci = 0; ci < nc; ++ci) {
      int col = cand[ci]*256 + tid;
      if (col < KN) {
        float key = gumbel_(urow[col]) + b_up[col];  // identical DAG to k_score_all
        if (packsc_(key, col) >= pthr) {
          float sc = key;                            // exact score
#pragma unroll
          for (int k = 0; k < KH; ++k) sc = fmaf(hs[k], W_up[k*KN + col], sc);
          unsigned long long pk = packsc_(sc, col);
          if (pk > best) best = pk;
        }
      }
    }
    // block-reduce best: wave shuffle then 4-way merge
#pragma unroll
    for (int d = 32; d > 0; d >>= 1) {
      unsigned long long q = (unsigned long long)__shfl_xor((long long)best, d, 64);
      if (q > best) best = q;
    }
    if (lane == 0) sp[wave] = best;
    __syncthreads();
    if (tid == 0) {
      unsigned long long fb = sp[0];
      if (sp[1] > fb) fb = sp[1];
      if (sp[2] > fb) fb = sp[2];
      if (sp[3] > fb) fb = sp[3];
      int w = (int)(~(unsigned)(fb & 0xFFFFFFFFull));
      widxS = w;
      idx[(size_t)t*KNS + s] = w;
    }
    __syncthreads();
    // --- LSTM advance for next step ---
    if (t < KRW - 1) {
      int widx = widxS;
      if (tid < KDW) xs[tid] = W_down[(size_t)widx*KDW + tid];
      __syncthreads();
      if (tid < 4*KH) {
        float a = b_ih[tid] + b_hh[tid];
#pragma unroll 8
        for (int k = 0; k < KDW; ++k) a = fmaf(xs[k], w_ih[k*4*KH + tid], a);
#pragma unroll 8
        for (int k = 0; k < KH; ++k) a = fmaf(hs[k], w_hh[k*4*KH + tid], a);
        g[tid] = a;
      }
      __syncthreads();
      if (tid < KH) {
        float gi = g[tid], gf = g[KH+tid], gg2 = g[2*KH+tid], go = g[3*KH+tid];
        float cn = sigmoidf_(gf) * cs[tid] + sigmoidf_(gi) * tanhf(gg2);
        float hn = sigmoidf_(go) * tanhf(cn);
        hs[tid] = hn; cs[tid] = cn;
      }
      __syncthreads();
      if (wave == 0) {
        float x = (lane < KH) ? hs[lane] : 0.f;
        float v = x * x;
#pragma unroll
        for (int d = 32; d > 0; d >>= 1) v += __shfl_xor(v, d, 64);
        if (lane == 0) hnS = sqrtf(v);
      }
      __syncthreads();
    }
  }
}

// ------- phase C: pure streaming one-hot write, grid (NS, RW) -------
__global__ void __launch_bounds__(256) k_onehot(const int* __restrict__ idx,
                                                float* __restrict__ out) {
  int s = blockIdx.x, t = blockIdx.y;
  int widx = idx[(size_t)t*KNS + s];
  floatx4* row = (floatx4*)(out + ((size_t)s*KRW + t)*KN);
  for (int j = threadIdx.x; j < KN/4; j += 256) {
    floatx4 v = (floatx4)(0.f);
    int d = widx - j*4;
    if (d >= 0 && d < 4) v[d] = 1.f;
    __builtin_nontemporal_store(v, row + j);
  }
}

extern "C" void kernel_launch(void* const* d_in, const int* in_sizes, int n_in,
                              void* d_out, int out_size, void* d_ws, size_t ws_size,
                              hipStream_t stream) {
  const float* z      = (const float*)d_in[0];
  const float* gu     = (const float*)d_in[1];
  const float* l1w    = (const float*)d_in[2];
  const float* l1b    = (const float*)d_in[3];
  const float* l2w    = (const float*)d_in[4];
  const float* l2b    = (const float*)d_in[5];
  const float* l3w    = (const float*)d_in[6];
  const float* l3b    = (const float*)d_in[7];
  const float* w_ih   = (const float*)d_in[8];
  const float* w_hh   = (const float*)d_in[9];
  const float* b_ih   = (const float*)d_in[10];
  const float* b_hh   = (const float*)d_in[11];
  const float* W_up   = (const float*)d_in[12];
  const float* b_up   = (const float*)d_in[13];
  const float* W_down = (const float*)d_in[14];
  float* out = (float*)d_out;

  // workspace layout (~2.8 MB)
  char* ws = (char*)d_ws;
  float* h  = (float*)(ws);                                    // 512*40 f32
  float* c  = (float*)(ws + (size_t)KNS*KH*4);                 // 512*40 f32
  unsigned long long* pp = (unsigned long long*)(ws + (size_t)2*KNS*KH*4);  // 8*512*79 u64
  int*   idx   = (int*)  (ws + (size_t)2*KNS*KH*4 + (size_t)KRW*KNS*KCH*8); // 8*512 i32
  float* wnmax = (float*)(ws + (size_t)2*KNS*KH*4 + (size_t)KRW*KNS*KCH*8 + (size_t)KRW*KNS*4);

  hipMemsetAsync(wnmax, 0, 4, stream);
  k_wnorm<<<(KN + 255)/256, 256, 0, stream>>>(W_up, wnmax);
  k_init<<<KNS, 256, 0, stream>>>(z, l1w, l1b, l2w, l2b, l3w, l3b, b_ih, b_hh, w_hh, h, c);

  k_score_all<<<dim3(KCH, 16, KRW), 256, 0, stream>>>(gu, b_up, pp);

  k_resolve<<<KNS, 256, 0, stream>>>(pp, gu, W_up, b_up, wnmax, h, c,
                                     W_down, w_ih, w_hh, b_ih, b_hh, idx);

  k_onehot<<<dim3(KNS, KRW), 256, 0, stream>>>(idx, out);
}